// Round 1
// 992.803 us; speedup vs baseline: 1.0201x; 1.0201x over previous
//
#include <hip/hip_runtime.h>

typedef short bf16x8 __attribute__((ext_vector_type(8)));
typedef float floatx4 __attribute__((ext_vector_type(4)));
typedef unsigned short u16x4 __attribute__((ext_vector_type(4)));
typedef unsigned short u16x8 __attribute__((ext_vector_type(8)));

__device__ __forceinline__ unsigned short f2bf(float f) {
  union { float f; unsigned int u; } v;
  v.f = f;
  unsigned int u = v.u + (0x7FFFu + ((v.u >> 16) & 1u));  // RNE
  return (unsigned short)(u >> 16);
}

__device__ __forceinline__ bf16x8 pack8(float4 a, float4 b) {
  u16x8 h;
  h[0] = f2bf(a.x); h[1] = f2bf(a.y); h[2] = f2bf(a.z); h[3] = f2bf(a.w);
  h[4] = f2bf(b.x); h[5] = f2bf(b.y); h[6] = f2bf(b.z); h[7] = f2bf(b.w);
  union { u16x8 u; bf16x8 s; } cv; cv.u = h; return cv.s;
}

// ---------------------------------------------------------------------------
// Pack weights to bf16 fragment layout Wf[g][n][j] = W[g*8+j][n] (g=k/8,j=k%8)
// so a lane's B-fragment (8 bf16 along k) is 16 contiguous bytes.
// ---------------------------------------------------------------------------
__global__ __launch_bounds__(256) void prep_weights(
    const float* __restrict__ mW1, const float* __restrict__ mW2,
    const float* __restrict__ nW1, const float* __restrict__ nW2,
    unsigned short* __restrict__ W1f, unsigned short* __restrict__ W2f,
    unsigned short* __restrict__ NW1f, unsigned short* __restrict__ NW2f) {
  int idx = blockIdx.x * 256 + threadIdx.x;
  if (idx < 24576) {
    int j = idx & 7, n = (idx >> 3) & 127, g = idx >> 10;
    W1f[idx] = f2bf(mW1[(g * 8 + j) * 128 + n]);
  } else if (idx < 32768) {
    int t = idx - 24576;
    int j = t & 7, n = (t >> 3) & 63, g = t >> 9;
    W2f[t] = f2bf(mW2[(g * 8 + j) * 64 + n]);
  } else if (idx < 49152) {
    int t = idx - 32768;
    int j = t & 7, n = (t >> 3) & 127, g = t >> 10;
    NW1f[t] = f2bf(nW1[(g * 8 + j) * 128 + n]);
  } else if (idx < 57344) {
    int t = idx - 49152;
    int j = t & 7, n = (t >> 3) & 63, g = t >> 9;
    NW2f[t] = f2bf(nW2[(g * 8 + j) * 64 + n]);
  }
}

// nodes fp32 -> bf16 once (removes per-edge converts; halves gather bytes)
__global__ __launch_bounds__(256) void conv_nodes(
    const float* __restrict__ nodes, unsigned short* __restrict__ nodes_bf, int total4) {
  int i = (blockIdx.x * 256 + threadIdx.x) * 4;
  if (i < total4) {
    float4 v = *(const float4*)(nodes + i);
    u16x4 h; h[0] = f2bf(v.x); h[1] = f2bf(v.y); h[2] = f2bf(v.z); h[3] = f2bf(v.w);
    *(u16x4*)(nodes_bf + i) = h;
  }
}

// ---------------------------------------------------------------------------
// Edge kernel, barrier-minimal: A- and B-fragments load DIRECTLY from global
// into registers (16 B/lane, used once; weights L2-hot). Only LDS use is the
// C-layout -> A-layout transform of H (one __syncthreads in the whole kernel).
// H stored in fragment order Hf[g][row][j] (g=k/8, j=k%8): 32 KB exactly,
// so 4 blocks/CU fit even under a 128 KiB workgroup-LDS budget (was 34816 B
// = 3 blocks/CU -> occupancy 33.7%, the latency-bound signature).
// ---------------------------------------------------------------------------
__global__ __launch_bounds__(256, 4) void edge_kernel(
    const float* __restrict__ edges, const unsigned short* __restrict__ nodes_bf,
    const int* __restrict__ senders, const int* __restrict__ receivers,
    const unsigned short* __restrict__ W1f, const unsigned short* __restrict__ W2f,
    const float* __restrict__ b1, const float* __restrict__ b2,
    float* agg, int E) {
  __shared__ unsigned short Hf[16 * 128 * 8];  // [g=k/8][row][j=k%8], 32 KB

  const int tid = threadIdx.x;
  const int e0 = blockIdx.x * 128;
  const int w = tid >> 6, lane = tid & 63;
  const int col = lane & 15, quad = lane >> 4;
  const int wm = w & 1, wn = w >> 1;

  // gather indices for this lane's A-rows (row = wm*64 + mt*16 + col)
  int srow[4], sndi[4], rcvi[4];
#pragma unroll
  for (int mt = 0; mt < 4; ++mt) {
    int r = e0 + wm * 64 + mt * 16 + col;
    srow[mt] = r < E ? r : E - 1;
  }
#pragma unroll
  for (int mt = 0; mt < 4; ++mt) { sndi[mt] = senders[srow[mt]]; rcvi[mt] = receivers[srow[mt]]; }

  floatx4 z4 = {0.f, 0.f, 0.f, 0.f};
  floatx4 acc1[4][4];
#pragma unroll
  for (int mt = 0; mt < 4; ++mt)
#pragma unroll
    for (int nt = 0; nt < 4; ++nt) acc1[mt][nt] = z4;

  // GEMM1, K=192: slices 0,1 = sender feats; 2,3 = receiver feats; 4,5 = edge feats
#pragma unroll
  for (int ks = 0; ks < 4; ++ks) {
    bf16x8 a[4], b[4];
#pragma unroll
    for (int mt = 0; mt < 4; ++mt) {
      int nd = (ks < 2) ? sndi[mt] : rcvi[mt];
      a[mt] = *(const bf16x8*)&nodes_bf[(size_t)nd * 64 + (ks & 1) * 32 + quad * 8];
    }
#pragma unroll
    for (int nt = 0; nt < 4; ++nt)
      b[nt] = *(const bf16x8*)&W1f[ks * 4096 + quad * 1024 + (wn * 64 + nt * 16 + col) * 8];
#pragma unroll
    for (int mt = 0; mt < 4; ++mt)
#pragma unroll
      for (int nt = 0; nt < 4; ++nt)
        acc1[mt][nt] = __builtin_amdgcn_mfma_f32_16x16x32_bf16(a[mt], b[nt], acc1[mt][nt], 0, 0, 0);
  }
#pragma unroll
  for (int ks = 4; ks < 6; ++ks) {
    bf16x8 a[4], b[4];
#pragma unroll
    for (int mt = 0; mt < 4; ++mt) {
      const float* p = edges + (size_t)srow[mt] * 64 + (ks - 4) * 32 + quad * 8;
      float4 v0 = *(const float4*)p;
      float4 v1 = *(const float4*)(p + 4);
      a[mt] = pack8(v0, v1);
    }
#pragma unroll
    for (int nt = 0; nt < 4; ++nt)
      b[nt] = *(const bf16x8*)&W1f[ks * 4096 + quad * 1024 + (wn * 64 + nt * 16 + col) * 8];
#pragma unroll
    for (int mt = 0; mt < 4; ++mt)
#pragma unroll
      for (int nt = 0; nt < 4; ++nt)
        acc1[mt][nt] = __builtin_amdgcn_mfma_f32_16x16x32_bf16(a[mt], b[nt], acc1[mt][nt], 0, 0, 0);
  }

  // bias + ReLU -> Hf (bf16), C-layout -> A-fragment layout via LDS
#pragma unroll
  for (int nt = 0; nt < 4; ++nt) {
    float bias = b1[wn * 64 + nt * 16 + col];
    int c = wn * 64 + nt * 16 + col;
    unsigned short* dst = &Hf[((c >> 3) * 128) * 8 + (c & 7)];
#pragma unroll
    for (int mt = 0; mt < 4; ++mt)
#pragma unroll
      for (int r = 0; r < 4; ++r) {
        float v = acc1[mt][nt][r] + bias;
        v = v > 0.f ? v : 0.f;
        int row = wm * 64 + mt * 16 + quad * 4 + r;
        dst[row * 8] = f2bf(v);
      }
  }
  __syncthreads();  // the only barrier

  floatx4 acc2[4][2];
#pragma unroll
  for (int mt = 0; mt < 4; ++mt) { acc2[mt][0] = z4; acc2[mt][1] = z4; }

  // GEMM2, K=128: A from LDS (16B contiguous fragment), B direct from global (L2-hot)
#pragma unroll
  for (int ks = 0; ks < 4; ++ks) {
    bf16x8 a[4], b[2];
#pragma unroll
    for (int mt = 0; mt < 4; ++mt)
      a[mt] = *(const bf16x8*)&Hf[((ks * 4 + quad) * 128 + (wm * 64 + mt * 16 + col)) * 8];
#pragma unroll
    for (int nt = 0; nt < 2; ++nt)
      b[nt] = *(const bf16x8*)&W2f[ks * 2048 + quad * 512 + (wn * 32 + nt * 16 + col) * 8];
#pragma unroll
    for (int mt = 0; mt < 4; ++mt)
#pragma unroll
      for (int nt = 0; nt < 2; ++nt)
        acc2[mt][nt] = __builtin_amdgcn_mfma_f32_16x16x32_bf16(a[mt], b[nt], acc2[mt][nt], 0, 0, 0);
  }

  float bs0 = b2[wn * 32 + col];
  float bs1 = b2[wn * 32 + 16 + col];
#pragma unroll
  for (int mt = 0; mt < 4; ++mt)
#pragma unroll
    for (int r = 0; r < 4; ++r) {
      int er = e0 + wm * 64 + mt * 16 + quad * 4 + r;
      if (er < E) {
        int rv = receivers[er];
        float v0 = acc2[mt][0][r] + bs0; v0 = v0 > 0.f ? v0 : 0.f;
        float v1 = acc2[mt][1][r] + bs1; v1 = v1 > 0.f ? v1 : 0.f;
        atomicAdd(&agg[(size_t)rv * 64 + wn * 32 + col], v0);
        atomicAdd(&agg[(size_t)rv * 64 + wn * 32 + 16 + col], v1);
      }
    }
}

// ---------------------------------------------------------------------------
// Node kernel, same barrier-minimal structure.
//   Y = concat(nodes, agg); H = relu(Y@W1+b1); y = H@W2+b2
//   out = nodes + LN(y)*scale + offset   (agg aliases d_out; block-local RAW)
// ---------------------------------------------------------------------------
__global__ __launch_bounds__(256, 3) void node_kernel(
    const float* __restrict__ nodes, const unsigned short* __restrict__ nodes_bf,
    const float* agg,
    const unsigned short* __restrict__ W1f, const unsigned short* __restrict__ W2f,
    const float* __restrict__ b1, const float* __restrict__ b2,
    const float* __restrict__ ln_s, const float* __restrict__ ln_o,
    float* out, int N) {
  __shared__ unsigned short Hf[16 * 128 * 8];  // 32 KB fragment-order hidden
  __shared__ float Ls1[128][2];
  __shared__ float Ls2[128][2];

  const int tid = threadIdx.x;
  const int n0 = blockIdx.x * 128;
  const int w = tid >> 6, lane = tid & 63;
  const int col = lane & 15, quad = lane >> 4;
  const int wm = w & 1, wn = w >> 1;

  int arow[4];
#pragma unroll
  for (int mt = 0; mt < 4; ++mt) {
    int r = n0 + wm * 64 + mt * 16 + col;
    arow[mt] = r < N ? r : N - 1;
  }

  floatx4 z4 = {0.f, 0.f, 0.f, 0.f};
  floatx4 acc1[4][4];
#pragma unroll
  for (int mt = 0; mt < 4; ++mt)
#pragma unroll
    for (int nt = 0; nt < 4; ++nt) acc1[mt][nt] = z4;

  // GEMM1, K=128: slices 0,1 = node feats (bf16); 2,3 = agg (fp32)
#pragma unroll
  for (int ks = 0; ks < 2; ++ks) {
    bf16x8 a[4], b[4];
#pragma unroll
    for (int mt = 0; mt < 4; ++mt)
      a[mt] = *(const bf16x8*)&nodes_bf[(size_t)arow[mt] * 64 + ks * 32 + quad * 8];
#pragma unroll
    for (int nt = 0; nt < 4; ++nt)
      b[nt] = *(const bf16x8*)&W1f[ks * 4096 + quad * 1024 + (wn * 64 + nt * 16 + col) * 8];
#pragma unroll
    for (int mt = 0; mt < 4; ++mt)
#pragma unroll
      for (int nt = 0; nt < 4; ++nt)
        acc1[mt][nt] = __builtin_amdgcn_mfma_f32_16x16x32_bf16(a[mt], b[nt], acc1[mt][nt], 0, 0, 0);
  }
#pragma unroll
  for (int ks = 2; ks < 4; ++ks) {
    bf16x8 a[4], b[4];
#pragma unroll
    for (int mt = 0; mt < 4; ++mt) {
      const float* p = agg + (size_t)arow[mt] * 64 + (ks - 2) * 32 + quad * 8;
      float4 v0 = *(const float4*)p;
      float4 v1 = *(const float4*)(p + 4);
      a[mt] = pack8(v0, v1);
    }
#pragma unroll
    for (int nt = 0; nt < 4; ++nt)
      b[nt] = *(const bf16x8*)&W1f[ks * 4096 + quad * 1024 + (wn * 64 + nt * 16 + col) * 8];
#pragma unroll
    for (int mt = 0; mt < 4; ++mt)
#pragma unroll
      for (int nt = 0; nt < 4; ++nt)
        acc1[mt][nt] = __builtin_amdgcn_mfma_f32_16x16x32_bf16(a[mt], b[nt], acc1[mt][nt], 0, 0, 0);
  }

#pragma unroll
  for (int nt = 0; nt < 4; ++nt) {
    float bias = b1[wn * 64 + nt * 16 + col];
    int c = wn * 64 + nt * 16 + col;
    unsigned short* dst = &Hf[((c >> 3) * 128) * 8 + (c & 7)];
#pragma unroll
    for (int mt = 0; mt < 4; ++mt)
#pragma unroll
      for (int r = 0; r < 4; ++r) {
        float v = acc1[mt][nt][r] + bias;
        v = v > 0.f ? v : 0.f;
        int row = wm * 64 + mt * 16 + quad * 4 + r;
        dst[row * 8] = f2bf(v);
      }
  }
  __syncthreads();

  floatx4 acc2[4][2];
#pragma unroll
  for (int mt = 0; mt < 4; ++mt) { acc2[mt][0] = z4; acc2[mt][1] = z4; }

#pragma unroll
  for (int ks = 0; ks < 4; ++ks) {
    bf16x8 a[4], b[2];
#pragma unroll
    for (int mt = 0; mt < 4; ++mt)
      a[mt] = *(const bf16x8*)&Hf[((ks * 4 + quad) * 128 + (wm * 64 + mt * 16 + col)) * 8];
#pragma unroll
    for (int nt = 0; nt < 2; ++nt)
      b[nt] = *(const bf16x8*)&W2f[ks * 2048 + quad * 512 + (wn * 32 + nt * 16 + col) * 8];
#pragma unroll
    for (int mt = 0; mt < 4; ++mt)
#pragma unroll
      for (int nt = 0; nt < 2; ++nt)
        acc2[mt][nt] = __builtin_amdgcn_mfma_f32_16x16x32_bf16(a[mt], b[nt], acc2[mt][nt], 0, 0, 0);
  }

  // bias
  float y[4][2][4];
  float bs0 = b2[wn * 32 + col];
  float bs1 = b2[wn * 32 + 16 + col];
#pragma unroll
  for (int mt = 0; mt < 4; ++mt)
#pragma unroll
    for (int r = 0; r < 4; ++r) {
      y[mt][0][r] = acc2[mt][0][r] + bs0;
      y[mt][1][r] = acc2[mt][1][r] + bs1;
    }

  // LayerNorm: reduce this wave's 32 cols across the 16-lane quad,
  // combine the two column-halves (wn=0/1) through LDS.
#pragma unroll
  for (int mt = 0; mt < 4; ++mt)
#pragma unroll
    for (int r = 0; r < 4; ++r) {
      float p1 = y[mt][0][r] + y[mt][1][r];
      float p2 = y[mt][0][r] * y[mt][0][r] + y[mt][1][r] * y[mt][1][r];
#pragma unroll
      for (int m = 1; m <= 8; m <<= 1) {
        p1 += __shfl_xor(p1, m);
        p2 += __shfl_xor(p2, m);
      }
      if (col == 0) {
        int row = wm * 64 + mt * 16 + quad * 4 + r;
        Ls1[row][wn] = p1;
        Ls2[row][wn] = p2;
      }
    }
  __syncthreads();

  float lsv0 = ln_s[wn * 32 + col], lsv1 = ln_s[wn * 32 + 16 + col];
  float lov0 = ln_o[wn * 32 + col], lov1 = ln_o[wn * 32 + 16 + col];
#pragma unroll
  for (int mt = 0; mt < 4; ++mt)
#pragma unroll
    for (int r = 0; r < 4; ++r) {
      int row = wm * 64 + mt * 16 + quad * 4 + r;
      int gi = n0 + row;
      float s1 = Ls1[row][0] + Ls1[row][1];
      float s2 = Ls2[row][0] + Ls2[row][1];
      float mean = s1 * (1.f / 64.f);
      float var = s2 * (1.f / 64.f) - mean * mean;
      float rstd = rsqrtf(var + 1e-5f);
      if (gi < N) {
        int j0 = wn * 32 + col;
        float o0 = (y[mt][0][r] - mean) * rstd * lsv0 + lov0 + nodes[(size_t)gi * 64 + j0];
        float o1 = (y[mt][1][r] - mean) * rstd * lsv1 + lov1 + nodes[(size_t)gi * 64 + j0 + 16];
        out[(size_t)gi * 64 + j0] = o0;
        out[(size_t)gi * 64 + j0 + 16] = o1;
      }
    }
}

extern "C" void kernel_launch(void* const* d_in, const int* in_sizes, int n_in,
                              void* d_out, int out_size, void* d_ws, size_t ws_size,
                              hipStream_t stream) {
  const float* nodes     = (const float*)d_in[0];
  const float* edges     = (const float*)d_in[1];
  const int*   senders   = (const int*)d_in[2];
  const int*   receivers = (const int*)d_in[3];
  const float* msg_W1    = (const float*)d_in[4];
  const float* msg_b1    = (const float*)d_in[5];
  const float* msg_W2    = (const float*)d_in[6];
  const float* msg_b2    = (const float*)d_in[7];
  const float* node_W1   = (const float*)d_in[8];
  const float* node_b1   = (const float*)d_in[9];
  const float* node_W2   = (const float*)d_in[10];
  const float* node_b2   = (const float*)d_in[11];
  const float* ln_scale  = (const float*)d_in[12];
  const float* ln_offset = (const float*)d_in[13];

  const int N = in_sizes[0] / 64;
  const int E = in_sizes[2];

  // Workspace: packed bf16 weights (114 KB) + bf16 nodes (12.8 MB).
  unsigned short* W1f  = (unsigned short*)d_ws;   // 24576
  unsigned short* W2f  = W1f + 24576;             // 8192
  unsigned short* NW1f = W2f + 8192;              // 16384
  unsigned short* NW2f = NW1f + 16384;            // 8192
  unsigned short* nodes_bf = NW2f + 8192;         // N*64

  float* agg = (float*)d_out;  // fp32 aggregation in-place in d_out

  hipMemsetAsync(d_out, 0, (size_t)out_size * sizeof(float), stream);
  prep_weights<<<224, 256, 0, stream>>>(msg_W1, msg_W2, node_W1, node_W2, W1f, W2f, NW1f, NW2f);
  conv_nodes<<<(N * 64 + 1023) / 1024, 256, 0, stream>>>(nodes, nodes_bf, N * 64);
  edge_kernel<<<(E + 127) / 128, 256, 0, stream>>>(edges, nodes_bf, senders, receivers,
                                                   W1f, W2f, msg_b1, msg_b2, agg, E);
  node_kernel<<<(N + 127) / 128, 256, 0, stream>>>(nodes, nodes_bf, agg, NW1f, NW2f,
                                                   node_b1, node_b2, ln_scale, ln_offset,
                                                   (float*)d_out, N);
}